// Round 14
// baseline (293.936 us; speedup 1.0000x reference)
//
#include <hip/hip_runtime.h>
#include <hip/hip_bf16.h>

#define NRBF 20
#define KAUG 24   // 20 rbf + env(bias row) + 3 zero pad, stored f16
#define DMAX 64   // padded slots per node (deg ~ Poisson(<=16); P(>64) ~ 1e-19)

typedef __attribute__((ext_vector_type(8))) short short8;
typedef __attribute__((ext_vector_type(4))) float float4v;
typedef __attribute__((ext_vector_type(2))) _Float16 half2v;
typedef unsigned short ushort_t;

__device__ __forceinline__ float bf2f(ushort_t u) {
    return __uint_as_float(((unsigned)u) << 16);
}
__device__ __forceinline__ ushort_t f2bf(float f) {
    unsigned u = __float_as_uint(f);
    u += 0x7FFF + ((u >> 16) & 1);   // round-to-nearest-even
    return (ushort_t)(u >> 16);
}
__device__ __forceinline__ float ldin(const void* p, size_t idx, int isbf) {
    return isbf ? bf2f(((const ushort_t*)p)[idx]) : ((const float*)p)[idx];
}
__device__ __forceinline__ void stout(void* p, size_t idx, float v, int isbf) {
    if (isbf) ((ushort_t*)p)[idx] = f2bf(v);
    else      ((float*)p)[idx] = v;
}
__device__ __forceinline__ float dot2(half2v a, half2v b, float c) {
#if __has_builtin(__builtin_amdgcn_fdot2)
    return __builtin_amdgcn_fdot2(a, b, c, false);
#else
    return c + (float)a.x * (float)b.x + (float)a.y * (float)b.y;
#endif
}

// view a 16B float4 register quad as 4 half2 lanes (free re-alias, no moves)
union F4H {
    float4v f;
    half2v  h[4];
};

// ---------------- dtype detect + cursor zero (fused) ----------------
__global__ void detect_kernel(const void* __restrict__ xyz, int* __restrict__ flag,
                              int* __restrict__ cursor, int N) {
    int idx = blockIdx.x * blockDim.x + threadIdx.x;
    if (idx < N) cursor[idx] = 0;
    if (blockIdx.x == 0 && threadIdx.x < 64) {
        const ushort_t* u = (const ushort_t*)xyz;
        unsigned e0 = (u[2 * threadIdx.x] >> 7) & 0xFF;
        unsigned long long bad = __ballot(e0 >= 0x90);
        if (threadIdx.x == 0) *flag = (__popcll(bad) > 2) ? 0 : 1;  // 1=bf16, 0=f32
    }
}

// ---------------- fused prep kernel ----------------
// Replaces prelude + scan + pack (3 dispatches -> 1). Padded CSR (DMAX
// slots/node), slot claimed by atomicAdd(cursor[i]). rbfh row stored as
// 3 x dwordx4 (R13 win).
__global__ void prep_kernel(const void* __restrict__ xyz, const int* __restrict__ nbr,
                            const void* __restrict__ cg_s,
                            const void* __restrict__ W1, const void* __restrict__ W2,
                            const void* __restrict__ Wr, const void* __restrict__ br,
                            float* __restrict__ s_acc, ushort_t* __restrict__ s_hi,
                            ushort_t* __restrict__ s_lo, int* __restrict__ cursor,
                            int* __restrict__ jlist, float4* __restrict__ upos,
                            _Float16* __restrict__ rbfh,
                            ushort_t* __restrict__ B1hi, ushort_t* __restrict__ B1lo,
                            ushort_t* __restrict__ B2hi, ushort_t* __restrict__ B2lo,
                            _Float16* __restrict__ WrT,
                            int N128, int E, const int* __restrict__ flagp) {
    int isbf = *flagp;
    int idx = blockIdx.x * blockDim.x + threadIdx.x;

    // ---- edge pack (padded CSR) ----
    if (idx < E) {
        int i = nbr[2 * idx], j = nbr[2 * idx + 1];
        float dx = ldin(xyz, 3 * j,     isbf) - ldin(xyz, 3 * i,     isbf);
        float dy = ldin(xyz, 3 * j + 1, isbf) - ldin(xyz, 3 * i + 1, isbf);
        float dz = ldin(xyz, 3 * j + 2, isbf) - ldin(xyz, 3 * i + 2, isbf);
        float dist = sqrtf(dx * dx + dy * dy + dz * dz + 3e-15f);
        if (dist < 5.0f) {
            constexpr float PI = 3.14159265358979323846f;
            float ev = 0.5f * (cosf(PI * dist * 0.2f) + 1.0f);
            int c = atomicAdd(&cursor[i], 1);
            if (c < DMAX) {
                size_t pos = (size_t)i * DMAX + c;
                jlist[pos] = j;
                float inv = 1.0f / dist;
                upos[pos] = make_float4(dx * inv, dy * inv, dz * inv, ev);
                constexpr double EM5 = 0.006737946999085467;  // exp(-5)
                constexpr float MU0 = (float)EM5;
                constexpr float DMU = (float)((1.0 - EM5) / 19.0);
                constexpr float BETA =
                    (float)(1.0 / ((0.1 * (1.0 - EM5)) * (0.1 * (1.0 - EM5))));
                float ed = expf(-dist);
                _Float16 rv[KAUG];
                #pragma unroll
                for (int k = 0; k < NRBF; k++) {
                    float dmu = ed - (MU0 + k * DMU);
                    rv[k] = (_Float16)(ev * expf(-BETA * dmu * dmu));
                }
                rv[NRBF] = (_Float16)ev;
                #pragma unroll
                for (int k = NRBF + 1; k < KAUG; k++) rv[k] = (_Float16)0.f;
                F4H o[3];
                #pragma unroll
                for (int r = 0; r < 3; r++) {
                    #pragma unroll
                    for (int q = 0; q < 4; q++) {
                        half2v h2;
                        h2.x = rv[r * 8 + 2 * q];
                        h2.y = rv[r * 8 + 2 * q + 1];
                        o[r].h[q] = h2;
                    }
                }
                float4v* rp4 = (float4v*)(rbfh + pos * KAUG);
                rp4[0] = o[0].f; rp4[1] = o[1].f; rp4[2] = o[2].f;
            }
        }
    }
    // ---- s init ----
    if (idx < N128) {
        float v = ldin(cg_s, idx, isbf);
        s_acc[idx] = v;
        ushort_t hi = f2bf(v);
        s_hi[idx] = hi;
        s_lo[idx] = f2bf(v - bf2f(hi));
    }
    // ---- weight prep ----
    const int NW1 = 3 * 4 * 8 * 64;
    const int NW2 = 3 * 4 * 24 * 64;
    const int NWT = 3 * 384;
    if (idx < NW1) {
        int lane = idx & 63;
        int t = idx >> 6;
        int nt = t % 8; t /= 8;
        int ks = t % 4; int l = t / 4;
        int n = lane & 15, quad = lane >> 4;
        int col = nt * 16 + n;
        size_t base = (size_t)l * 128 * 128;
        size_t fo = (size_t)idx * 8;
        #pragma unroll
        for (int j = 0; j < 8; j++) {
            int k = ks * 32 + quad * 8 + j;
            float v = ldin(W1, base + (size_t)k * 128 + col, isbf);
            ushort_t hi = f2bf(v);
            B1hi[fo + j] = hi;
            B1lo[fo + j] = f2bf(v - bf2f(hi));
        }
    } else if (idx < NW1 + NW2) {
        int i2 = idx - NW1;
        int lane = i2 & 63;
        int t = i2 >> 6;
        int nt = t % 24; t /= 24;
        int ks = t % 4; int l = t / 4;
        int n = lane & 15, quad = lane >> 4;
        int col = nt * 16 + n;
        size_t base = (size_t)l * 128 * 384;
        size_t fo = (size_t)i2 * 8;
        #pragma unroll
        for (int j = 0; j < 8; j++) {
            int k = ks * 32 + quad * 8 + j;
            float v = ldin(W2, base + (size_t)k * 384 + col, isbf);
            ushort_t hi = f2bf(v);
            B2hi[fo + j] = hi;
            B2lo[fo + j] = f2bf(v - bf2f(hi));
        }
    } else if (idx < NW1 + NW2 + NWT) {
        int i2 = idx - NW1 - NW2;
        int l = i2 / 384, col = i2 % 384;
        _Float16* wt = WrT + ((size_t)l * 384 + col) * KAUG;
        #pragma unroll
        for (int k = 0; k < KAUG; k++) {
            float v = 0.f;
            if (k < NRBF) v = ldin(Wr, ((size_t)l * NRBF + k) * 384 + col, isbf);
            else if (k == NRBF) v = ldin(br, (size_t)l * 384 + col, isbf);
            wt[k] = (_Float16)v;
        }
    }
}

// ---------------- MFMA GEMM with RG row-groups per block ----------------
// R11 (+RG=2 GEMM2), R13 (+RG=2 GEMM1) both won; R14 doubles to RG=4: B-frags
// loop-invariant in registers, reused across 4 independent 64-row chains
// (A-loads of group rg+1 overlap MFMAs of group rg); B/bias traffic /4.
template <int ACT, int OUTMODE, int NTILES, int RG>
__global__ __launch_bounds__(256) void mfma_gemm_rg(
    const ushort_t* __restrict__ Ahi, const ushort_t* __restrict__ Alo,
    const ushort_t* __restrict__ Bhi, const ushort_t* __restrict__ Blo,
    const void* __restrict__ bias, size_t biasoff,
    ushort_t* __restrict__ out_hi, ushort_t* __restrict__ out_lo,
    int M, const int* __restrict__ flagp) {
    constexpr int Ncols = NTILES * 16;
    int isbf = *flagp;
    int nt = blockIdx.x % NTILES;
    int bxg = blockIdx.x / NTILES;
    int tid = threadIdx.x;
    int wave = tid >> 6, lane = tid & 63;
    int m = lane & 15, quad = lane >> 4;
    short8 zero8 = {};

    // hoist B fragments (per-ks) into registers
    short8 bh[4], bl[4];
    #pragma unroll
    for (int ks = 0; ks < 4; ks++) {
        size_t fo = (((size_t)ks * NTILES + nt) * 64 + lane) * 8;
        bh[ks] = *reinterpret_cast<const short8*>(Bhi + fo);
        bl[ks] = isbf ? zero8 : *reinterpret_cast<const short8*>(Blo + fo);
    }
    int col = nt * 16 + m;
    float bv = ldin(bias, biasoff + col, isbf);

    #pragma unroll
    for (int rg = 0; rg < RG; rg++) {
        int bx = bxg * RG + rg;
        int brow = bx * 64 + wave * 16;
        int row = brow + m;
        float4v acc = {};
        #pragma unroll
        for (int ks = 0; ks < 4; ks++) {
            short8 ah = zero8, al = zero8;
            if (row < M) {
                size_t ao = (size_t)row * 128 + ks * 32 + quad * 8;
                ah = *reinterpret_cast<const short8*>(Ahi + ao);
                al = *reinterpret_cast<const short8*>(Alo + ao);
            }
            acc = __builtin_amdgcn_mfma_f32_16x16x32_bf16(ah, bh[ks], acc, 0, 0, 0);
            acc = __builtin_amdgcn_mfma_f32_16x16x32_bf16(al, bh[ks], acc, 0, 0, 0);
            if (!isbf) {
                acc = __builtin_amdgcn_mfma_f32_16x16x32_bf16(ah, bl[ks], acc, 0, 0, 0);
            }
        }
        #pragma unroll
        for (int r = 0; r < 4; r++) {
            int orow = brow + quad * 4 + r;
            if (orow >= M) continue;
            float x = acc[r] + bv;
            if (ACT) x = x / (1.0f + expf(-x));  // silu
            size_t oo = (size_t)orow * Ncols + col;
            ushort_t h = f2bf(x);
            out_hi[oo] = h;
            if (OUTMODE == 0) out_lo[oo] = f2bf(x - bf2f(h));
        }
    }
}

// ---------------- node gather kernel (R7/R11 form — AT ITS ROOFLINE) ----------
// One block per node, 128 threads; thread tt owns features {tt, 128+tt, 256+tt}.
// CLOSED: moves 112MB (FETCH 79.7 + WRITE 32.5) in 42.5us = 2.65 TB/s on a
// random-gather pattern — the achievable HBM ceiling for scattered 256-768B
// granules (15.4MB working set >> 4MB per-XCD L2 -> ~5x refetch, irreducible).
// R8 (reg pipeline), R9 (barrier split), R10 (8-node pack), R12 (persistent)
// ALL regressed. Do not restructure.
template <int L0, int LAST>
__global__ __launch_bounds__(128, 8) void node_kernel(
    const int* __restrict__ cursor, const int* __restrict__ jlist,
    const float4* __restrict__ upos, const _Float16* __restrict__ rbfh,
    const _Float16* __restrict__ WrT,
    const ushort_t* __restrict__ phi,
    const float* __restrict__ v_old, const ushort_t* __restrict__ vh_old,
    float* __restrict__ s_acc, ushort_t* __restrict__ s_hi, ushort_t* __restrict__ s_lo,
    float* __restrict__ v_new, ushort_t* __restrict__ vh_new,
    void* __restrict__ out, int N, const int* __restrict__ flagp) {
    int isbf = *flagp;
    int tt = threadIdx.x;
    int node = blockIdx.x;

    // hoist this thread's 3 WrT columns: 3 x float4 (48B) each, 9 loads total
    F4H wc0[3], wc1[3], wc2[3];
    {
        const float4v* w0p = (const float4v*)(WrT + (size_t)tt * KAUG);
        const float4v* w1p = (const float4v*)(WrT + (size_t)(tt + 128) * KAUG);
        const float4v* w2p = (const float4v*)(WrT + (size_t)(tt + 256) * KAUG);
        #pragma unroll
        for (int r = 0; r < 3; r++) {
            wc0[r].f = w0p[r]; wc1[r].f = w1p[r]; wc2[r].f = w2p[r];
        }
    }
    int cnt   = __builtin_amdgcn_readfirstlane(cursor[node]);
    if (cnt > DMAX) cnt = DMAX;
    int start = node * DMAX;
    int end   = start + cnt;

    float dsv = 0.f, ax = 0.f, ay = 0.f, az = 0.f;
    // scalar j prefetch: j for edge k is loaded during iteration k-1
    int j = (start < end) ? __builtin_amdgcn_readfirstlane(jlist[start]) : 0;
    for (int k = start; k < end; k++) {
        int jn = j;
        if (k + 1 < end) jn = __builtin_amdgcn_readfirstlane(jlist[k + 1]);
        float4 u4 = upos[k];
        const float4v* rp4 = (const float4v*)(rbfh + (size_t)k * KAUG);
        F4H rv0, rv1, rv2;
        rv0.f = rp4[0]; rv1.f = rp4[1]; rv2.f = rp4[2];
        float w0 = 0.f, w1 = 0.f, w2 = 0.f;
        #pragma unroll
        for (int q = 0; q < 4; q++) {
            w0 = dot2(rv0.h[q], wc0[0].h[q], w0);
            w1 = dot2(rv0.h[q], wc1[0].h[q], w1);
            w2 = dot2(rv0.h[q], wc2[0].h[q], w2);
        }
        #pragma unroll
        for (int q = 0; q < 4; q++) {
            w0 = dot2(rv1.h[q], wc0[1].h[q], w0);
            w1 = dot2(rv1.h[q], wc1[1].h[q], w1);
            w2 = dot2(rv1.h[q], wc2[1].h[q], w2);
        }
        #pragma unroll
        for (int q = 0; q < 4; q++) {
            w0 = dot2(rv2.h[q], wc0[2].h[q], w0);
            w1 = dot2(rv2.h[q], wc1[2].h[q], w1);
            w2 = dot2(rv2.h[q], wc2[2].h[q], w2);
        }
        size_t jb = (size_t)j * 384;
        dsv += bf2f(phi[jb + tt]) * w0;
        float gv = bf2f(phi[jb + 128 + tt]) * w1;
        float gu = bf2f(phi[jb + 256 + tt]) * w2;
        if (L0) {
            ax += gu * u4.x; ay += gu * u4.y; az += gu * u4.z;
        } else {
            const ushort_t* vj = &vh_old[jb + (size_t)tt * 3];
            ax += gu * u4.x + gv * bf2f(vj[0]);
            ay += gu * u4.y + gv * bf2f(vj[1]);
            az += gu * u4.z + gv * bf2f(vj[2]);
        }
        j = jn;
    }
    size_t so = (size_t)node * 128 + tt;
    float snew = s_acc[so] + dsv;
    size_t ib = (size_t)node * 384 + (size_t)tt * 3;
    float vx = L0 ? ax : v_old[ib]     + ax;
    float vy = L0 ? ay : v_old[ib + 1] + ay;
    float vz = L0 ? az : v_old[ib + 2] + az;
    if (LAST) {
        stout(out, so, snew, isbf);
        size_t ob = (size_t)N * 128 + ib;
        stout(out, ob,     vx, isbf);
        stout(out, ob + 1, vy, isbf);
        stout(out, ob + 2, vz, isbf);
    } else {
        s_acc[so] = snew;
        ushort_t hi = f2bf(snew);
        s_hi[so] = hi;
        s_lo[so] = f2bf(snew - bf2f(hi));
        v_new[ib] = vx; v_new[ib + 1] = vy; v_new[ib + 2] = vz;
        vh_new[ib]     = f2bf(vx);
        vh_new[ib + 1] = f2bf(vy);
        vh_new[ib + 2] = f2bf(vz);
    }
}

extern "C" void kernel_launch(void* const* d_in, const int* in_sizes, int n_in,
                              void* d_out, int out_size, void* d_ws, size_t ws_size,
                              hipStream_t stream) {
    const int N = in_sizes[0] / 3;
    const int E = in_sizes[1] / 2;
    const void* xyz  = d_in[0];
    const int*  nbr  = (const int*)d_in[1];
    const void* cg_s = d_in[2];
    const void* W1   = d_in[3];
    const void* b1   = d_in[4];
    const void* W2   = d_in[5];
    const void* b2   = d_in[6];
    const void* Wr   = d_in[7];
    const void* br   = d_in[8];

    size_t off = 0;
    auto alloc = [&](size_t bytes) -> char* {
        char* p = (char*)d_ws + off;
        off = (off + bytes + 63) & ~(size_t)63;
        return p;
    };
    int*       flag   = (int*)alloc(64);
    float*     s_acc  = (float*)alloc((size_t)N * 128 * 4);
    float*     vA     = (float*)alloc((size_t)N * 384 * 4);
    float*     vB     = (float*)alloc((size_t)N * 384 * 4);
    int*       cursor = (int*)alloc((size_t)N * 4);
    int*       jlist  = (int*)alloc((size_t)N * DMAX * 4);
    float4*    upos   = (float4*)alloc((size_t)N * DMAX * 16);
    _Float16*  rbfh   = (_Float16*)alloc((size_t)N * DMAX * KAUG * 2);
    _Float16*  WrT    = (_Float16*)alloc((size_t)3 * 384 * KAUG * 2);
    ushort_t*  s_hi   = (ushort_t*)alloc((size_t)N * 128 * 2);
    ushort_t*  s_lo   = (ushort_t*)alloc((size_t)N * 128 * 2);
    ushort_t*  h_hi   = (ushort_t*)alloc((size_t)N * 128 * 2);
    ushort_t*  h_lo   = (ushort_t*)alloc((size_t)N * 128 * 2);
    ushort_t*  phi    = (ushort_t*)alloc((size_t)N * 384 * 2);
    ushort_t*  vhA    = (ushort_t*)alloc((size_t)N * 384 * 2);
    ushort_t*  vhB    = (ushort_t*)alloc((size_t)N * 384 * 2);
    ushort_t*  B1hi   = (ushort_t*)alloc((size_t)3 * 4 * 8 * 64 * 8 * 2);
    ushort_t*  B1lo   = (ushort_t*)alloc((size_t)3 * 4 * 8 * 64 * 8 * 2);
    ushort_t*  B2hi   = (ushort_t*)alloc((size_t)3 * 4 * 24 * 64 * 8 * 2);
    ushort_t*  B2lo   = (ushort_t*)alloc((size_t)3 * 4 * 24 * 64 * 8 * 2);

    detect_kernel<<<(N + 255) / 256, 256, 0, stream>>>(xyz, flag, cursor, N);

    const int N128 = N * 128;
    const int pg = (max(E, N128) + 255) / 256;
    prep_kernel<<<pg, 256, 0, stream>>>(xyz, nbr, cg_s, W1, W2, Wr, br,
                                        s_acc, s_hi, s_lo, cursor,
                                        jlist, upos, rbfh,
                                        B1hi, B1lo, B2hi, B2lo, WrT,
                                        N128, E, flag);

    const int gx = (N + 63) / 64;
    const int gx4 = (gx + 3) / 4;   // RG=4 row-groups per block
    for (int l = 0; l < 3; l++) {
        mfma_gemm_rg<1, 0, 8, 4><<<gx4 * 8, 256, 0, stream>>>(
            s_hi, s_lo,
            B1hi + (size_t)l * 4 * 8 * 64 * 8, B1lo + (size_t)l * 4 * 8 * 64 * 8,
            b1, (size_t)l * 128, h_hi, h_lo, N, flag);
        mfma_gemm_rg<0, 1, 24, 4><<<gx4 * 24, 256, 0, stream>>>(
            h_hi, h_lo,
            B2hi + (size_t)l * 4 * 24 * 64 * 8, B2lo + (size_t)l * 4 * 24 * 64 * 8,
            b2, (size_t)l * 384, phi, (ushort_t*)nullptr, N, flag);
        const _Float16* wrt = WrT + (size_t)l * 384 * KAUG;
        if (l == 0) {
            node_kernel<1, 0><<<N, 128, 0, stream>>>(
                cursor, jlist, upos, rbfh, wrt, phi,
                vA, vhA, s_acc, s_hi, s_lo, vA, vhA, d_out, N, flag);
        } else if (l == 1) {
            node_kernel<0, 0><<<N, 128, 0, stream>>>(
                cursor, jlist, upos, rbfh, wrt, phi,
                vA, vhA, s_acc, s_hi, s_lo, vB, vhB, d_out, N, flag);
        } else {
            node_kernel<0, 1><<<N, 128, 0, stream>>>(
                cursor, jlist, upos, rbfh, wrt, phi,
                vB, vhB, s_acc, s_hi, s_lo, vB, vhB, d_out, N, flag);
        }
    }
}

// Round 15
// 291.444 us; speedup vs baseline: 1.0085x; 1.0085x over previous
//
#include <hip/hip_runtime.h>
#include <hip/hip_bf16.h>

#define NRBF 20
#define KAUG 24   // 20 rbf + env(bias row) + 3 zero pad, stored f16
#define DMAX 64   // padded slots per node (deg ~ Poisson(<=16); P(>64) ~ 1e-19)

typedef __attribute__((ext_vector_type(8))) short short8;
typedef __attribute__((ext_vector_type(4))) float float4v;
typedef __attribute__((ext_vector_type(2))) _Float16 half2v;
typedef unsigned short ushort_t;

__device__ __forceinline__ float bf2f(ushort_t u) {
    return __uint_as_float(((unsigned)u) << 16);
}
__device__ __forceinline__ ushort_t f2bf(float f) {
    unsigned u = __float_as_uint(f);
    u += 0x7FFF + ((u >> 16) & 1);   // round-to-nearest-even
    return (ushort_t)(u >> 16);
}
__device__ __forceinline__ float ldin(const void* p, size_t idx, int isbf) {
    return isbf ? bf2f(((const ushort_t*)p)[idx]) : ((const float*)p)[idx];
}
__device__ __forceinline__ void stout(void* p, size_t idx, float v, int isbf) {
    if (isbf) ((ushort_t*)p)[idx] = f2bf(v);
    else      ((float*)p)[idx] = v;
}
__device__ __forceinline__ float dot2(half2v a, half2v b, float c) {
#if __has_builtin(__builtin_amdgcn_fdot2)
    return __builtin_amdgcn_fdot2(a, b, c, false);
#else
    return c + (float)a.x * (float)b.x + (float)a.y * (float)b.y;
#endif
}

// view a 16B float4 register quad as 4 half2 lanes (free re-alias, no moves)
union F4H {
    float4v f;
    half2v  h[4];
};

// ---------------- dtype detect + cursor zero (fused) ----------------
__global__ void detect_kernel(const void* __restrict__ xyz, int* __restrict__ flag,
                              int* __restrict__ cursor, int N) {
    int idx = blockIdx.x * blockDim.x + threadIdx.x;
    if (idx < N) cursor[idx] = 0;
    if (blockIdx.x == 0 && threadIdx.x < 64) {
        const ushort_t* u = (const ushort_t*)xyz;
        unsigned e0 = (u[2 * threadIdx.x] >> 7) & 0xFF;
        unsigned long long bad = __ballot(e0 >= 0x90);
        if (threadIdx.x == 0) *flag = (__popcll(bad) > 2) ? 0 : 1;  // 1=bf16, 0=f32
    }
}

// ---------------- fused prep kernel ----------------
// Replaces prelude + scan + pack (3 dispatches -> 1). Padded CSR (DMAX
// slots/node), slot claimed by atomicAdd(cursor[i]). rbfh row stored as
// 3 x dwordx4 (R13 win).
__global__ void prep_kernel(const void* __restrict__ xyz, const int* __restrict__ nbr,
                            const void* __restrict__ cg_s,
                            const void* __restrict__ W1, const void* __restrict__ W2,
                            const void* __restrict__ Wr, const void* __restrict__ br,
                            float* __restrict__ s_acc, ushort_t* __restrict__ s_hi,
                            ushort_t* __restrict__ s_lo, int* __restrict__ cursor,
                            int* __restrict__ jlist, float4* __restrict__ upos,
                            _Float16* __restrict__ rbfh,
                            ushort_t* __restrict__ B1hi, ushort_t* __restrict__ B1lo,
                            ushort_t* __restrict__ B2hi, ushort_t* __restrict__ B2lo,
                            _Float16* __restrict__ WrT,
                            int N128, int E, const int* __restrict__ flagp) {
    int isbf = *flagp;
    int idx = blockIdx.x * blockDim.x + threadIdx.x;

    // ---- edge pack (padded CSR) ----
    if (idx < E) {
        int i = nbr[2 * idx], j = nbr[2 * idx + 1];
        float dx = ldin(xyz, 3 * j,     isbf) - ldin(xyz, 3 * i,     isbf);
        float dy = ldin(xyz, 3 * j + 1, isbf) - ldin(xyz, 3 * i + 1, isbf);
        float dz = ldin(xyz, 3 * j + 2, isbf) - ldin(xyz, 3 * i + 2, isbf);
        float dist = sqrtf(dx * dx + dy * dy + dz * dz + 3e-15f);
        if (dist < 5.0f) {
            constexpr float PI = 3.14159265358979323846f;
            float ev = 0.5f * (cosf(PI * dist * 0.2f) + 1.0f);
            int c = atomicAdd(&cursor[i], 1);
            if (c < DMAX) {
                size_t pos = (size_t)i * DMAX + c;
                jlist[pos] = j;
                float inv = 1.0f / dist;
                upos[pos] = make_float4(dx * inv, dy * inv, dz * inv, ev);
                constexpr double EM5 = 0.006737946999085467;  // exp(-5)
                constexpr float MU0 = (float)EM5;
                constexpr float DMU = (float)((1.0 - EM5) / 19.0);
                constexpr float BETA =
                    (float)(1.0 / ((0.1 * (1.0 - EM5)) * (0.1 * (1.0 - EM5))));
                float ed = expf(-dist);
                _Float16 rv[KAUG];
                #pragma unroll
                for (int k = 0; k < NRBF; k++) {
                    float dmu = ed - (MU0 + k * DMU);
                    rv[k] = (_Float16)(ev * expf(-BETA * dmu * dmu));
                }
                rv[NRBF] = (_Float16)ev;
                #pragma unroll
                for (int k = NRBF + 1; k < KAUG; k++) rv[k] = (_Float16)0.f;
                F4H o[3];
                #pragma unroll
                for (int r = 0; r < 3; r++) {
                    #pragma unroll
                    for (int q = 0; q < 4; q++) {
                        half2v h2;
                        h2.x = rv[r * 8 + 2 * q];
                        h2.y = rv[r * 8 + 2 * q + 1];
                        o[r].h[q] = h2;
                    }
                }
                float4v* rp4 = (float4v*)(rbfh + pos * KAUG);
                rp4[0] = o[0].f; rp4[1] = o[1].f; rp4[2] = o[2].f;
            }
        }
    }
    // ---- s init ----
    if (idx < N128) {
        float v = ldin(cg_s, idx, isbf);
        s_acc[idx] = v;
        ushort_t hi = f2bf(v);
        s_hi[idx] = hi;
        s_lo[idx] = f2bf(v - bf2f(hi));
    }
    // ---- weight prep ----
    const int NW1 = 3 * 4 * 8 * 64;
    const int NW2 = 3 * 4 * 24 * 64;
    const int NWT = 3 * 384;
    if (idx < NW1) {
        int lane = idx & 63;
        int t = idx >> 6;
        int nt = t % 8; t /= 8;
        int ks = t % 4; int l = t / 4;
        int n = lane & 15, quad = lane >> 4;
        int col = nt * 16 + n;
        size_t base = (size_t)l * 128 * 128;
        size_t fo = (size_t)idx * 8;
        #pragma unroll
        for (int j = 0; j < 8; j++) {
            int k = ks * 32 + quad * 8 + j;
            float v = ldin(W1, base + (size_t)k * 128 + col, isbf);
            ushort_t hi = f2bf(v);
            B1hi[fo + j] = hi;
            B1lo[fo + j] = f2bf(v - bf2f(hi));
        }
    } else if (idx < NW1 + NW2) {
        int i2 = idx - NW1;
        int lane = i2 & 63;
        int t = i2 >> 6;
        int nt = t % 24; t /= 24;
        int ks = t % 4; int l = t / 4;
        int n = lane & 15, quad = lane >> 4;
        int col = nt * 16 + n;
        size_t base = (size_t)l * 128 * 384;
        size_t fo = (size_t)i2 * 8;
        #pragma unroll
        for (int j = 0; j < 8; j++) {
            int k = ks * 32 + quad * 8 + j;
            float v = ldin(W2, base + (size_t)k * 384 + col, isbf);
            ushort_t hi = f2bf(v);
            B2hi[fo + j] = hi;
            B2lo[fo + j] = f2bf(v - bf2f(hi));
        }
    } else if (idx < NW1 + NW2 + NWT) {
        int i2 = idx - NW1 - NW2;
        int l = i2 / 384, col = i2 % 384;
        _Float16* wt = WrT + ((size_t)l * 384 + col) * KAUG;
        #pragma unroll
        for (int k = 0; k < KAUG; k++) {
            float v = 0.f;
            if (k < NRBF) v = ldin(Wr, ((size_t)l * NRBF + k) * 384 + col, isbf);
            else if (k == NRBF) v = ldin(br, (size_t)l * 384 + col, isbf);
            wt[k] = (_Float16)v;
        }
    }
}

// ---------------- MFMA GEMM with RG row-groups per block ----------------
// RG=2 is the measured optimum (R11 GEMM2 -5us, R13 GEMM1; R14's RG=4 was
// neutral-to-worse — the B-reuse curve flattens while TLP thins). B fragments
// hoisted to registers ONCE, reused across RG consecutive 64-row groups.
template <int ACT, int OUTMODE, int NTILES, int RG>
__global__ __launch_bounds__(256) void mfma_gemm_rg(
    const ushort_t* __restrict__ Ahi, const ushort_t* __restrict__ Alo,
    const ushort_t* __restrict__ Bhi, const ushort_t* __restrict__ Blo,
    const void* __restrict__ bias, size_t biasoff,
    ushort_t* __restrict__ out_hi, ushort_t* __restrict__ out_lo,
    int M, const int* __restrict__ flagp) {
    constexpr int Ncols = NTILES * 16;
    int isbf = *flagp;
    int nt = blockIdx.x % NTILES;
    int bxg = blockIdx.x / NTILES;
    int tid = threadIdx.x;
    int wave = tid >> 6, lane = tid & 63;
    int m = lane & 15, quad = lane >> 4;
    short8 zero8 = {};

    // hoist B fragments (per-ks) into registers
    short8 bh[4], bl[4];
    #pragma unroll
    for (int ks = 0; ks < 4; ks++) {
        size_t fo = (((size_t)ks * NTILES + nt) * 64 + lane) * 8;
        bh[ks] = *reinterpret_cast<const short8*>(Bhi + fo);
        bl[ks] = isbf ? zero8 : *reinterpret_cast<const short8*>(Blo + fo);
    }
    int col = nt * 16 + m;
    float bv = ldin(bias, biasoff + col, isbf);

    #pragma unroll
    for (int rg = 0; rg < RG; rg++) {
        int bx = bxg * RG + rg;
        int brow = bx * 64 + wave * 16;
        int row = brow + m;
        float4v acc = {};
        #pragma unroll
        for (int ks = 0; ks < 4; ks++) {
            short8 ah = zero8, al = zero8;
            if (row < M) {
                size_t ao = (size_t)row * 128 + ks * 32 + quad * 8;
                ah = *reinterpret_cast<const short8*>(Ahi + ao);
                al = *reinterpret_cast<const short8*>(Alo + ao);
            }
            acc = __builtin_amdgcn_mfma_f32_16x16x32_bf16(ah, bh[ks], acc, 0, 0, 0);
            acc = __builtin_amdgcn_mfma_f32_16x16x32_bf16(al, bh[ks], acc, 0, 0, 0);
            if (!isbf) {
                acc = __builtin_amdgcn_mfma_f32_16x16x32_bf16(ah, bl[ks], acc, 0, 0, 0);
            }
        }
        #pragma unroll
        for (int r = 0; r < 4; r++) {
            int orow = brow + quad * 4 + r;
            if (orow >= M) continue;
            float x = acc[r] + bv;
            if (ACT) x = x / (1.0f + expf(-x));  // silu
            size_t oo = (size_t)orow * Ncols + col;
            ushort_t h = f2bf(x);
            out_hi[oo] = h;
            if (OUTMODE == 0) out_lo[oo] = f2bf(x - bf2f(h));
        }
    }
}

// ---------------- node gather kernel (R7/R11 form — AT ITS ROOFLINE) ----------
// One block per node, 128 threads; thread tt owns features {tt, 128+tt, 256+tt}.
// CLOSED: moves 112MB (FETCH 79.7 + WRITE 32.5) in 42.5us = 2.65 TB/s on a
// random-gather pattern — the achievable HBM ceiling for scattered 256-768B
// granules (15.4MB working set >> 4MB per-XCD L2 -> ~5x refetch, irreducible).
// R8 (reg pipeline), R9 (barrier split), R10 (8-node pack), R12 (persistent)
// ALL regressed. Do not restructure.
template <int L0, int LAST>
__global__ __launch_bounds__(128, 8) void node_kernel(
    const int* __restrict__ cursor, const int* __restrict__ jlist,
    const float4* __restrict__ upos, const _Float16* __restrict__ rbfh,
    const _Float16* __restrict__ WrT,
    const ushort_t* __restrict__ phi,
    const float* __restrict__ v_old, const ushort_t* __restrict__ vh_old,
    float* __restrict__ s_acc, ushort_t* __restrict__ s_hi, ushort_t* __restrict__ s_lo,
    float* __restrict__ v_new, ushort_t* __restrict__ vh_new,
    void* __restrict__ out, int N, const int* __restrict__ flagp) {
    int isbf = *flagp;
    int tt = threadIdx.x;
    int node = blockIdx.x;

    // hoist this thread's 3 WrT columns: 3 x float4 (48B) each, 9 loads total
    F4H wc0[3], wc1[3], wc2[3];
    {
        const float4v* w0p = (const float4v*)(WrT + (size_t)tt * KAUG);
        const float4v* w1p = (const float4v*)(WrT + (size_t)(tt + 128) * KAUG);
        const float4v* w2p = (const float4v*)(WrT + (size_t)(tt + 256) * KAUG);
        #pragma unroll
        for (int r = 0; r < 3; r++) {
            wc0[r].f = w0p[r]; wc1[r].f = w1p[r]; wc2[r].f = w2p[r];
        }
    }
    int cnt   = __builtin_amdgcn_readfirstlane(cursor[node]);
    if (cnt > DMAX) cnt = DMAX;
    int start = node * DMAX;
    int end   = start + cnt;

    float dsv = 0.f, ax = 0.f, ay = 0.f, az = 0.f;
    // scalar j prefetch: j for edge k is loaded during iteration k-1
    int j = (start < end) ? __builtin_amdgcn_readfirstlane(jlist[start]) : 0;
    for (int k = start; k < end; k++) {
        int jn = j;
        if (k + 1 < end) jn = __builtin_amdgcn_readfirstlane(jlist[k + 1]);
        float4 u4 = upos[k];
        const float4v* rp4 = (const float4v*)(rbfh + (size_t)k * KAUG);
        F4H rv0, rv1, rv2;
        rv0.f = rp4[0]; rv1.f = rp4[1]; rv2.f = rp4[2];
        float w0 = 0.f, w1 = 0.f, w2 = 0.f;
        #pragma unroll
        for (int q = 0; q < 4; q++) {
            w0 = dot2(rv0.h[q], wc0[0].h[q], w0);
            w1 = dot2(rv0.h[q], wc1[0].h[q], w1);
            w2 = dot2(rv0.h[q], wc2[0].h[q], w2);
        }
        #pragma unroll
        for (int q = 0; q < 4; q++) {
            w0 = dot2(rv1.h[q], wc0[1].h[q], w0);
            w1 = dot2(rv1.h[q], wc1[1].h[q], w1);
            w2 = dot2(rv1.h[q], wc2[1].h[q], w2);
        }
        #pragma unroll
        for (int q = 0; q < 4; q++) {
            w0 = dot2(rv2.h[q], wc0[2].h[q], w0);
            w1 = dot2(rv2.h[q], wc1[2].h[q], w1);
            w2 = dot2(rv2.h[q], wc2[2].h[q], w2);
        }
        size_t jb = (size_t)j * 384;
        dsv += bf2f(phi[jb + tt]) * w0;
        float gv = bf2f(phi[jb + 128 + tt]) * w1;
        float gu = bf2f(phi[jb + 256 + tt]) * w2;
        if (L0) {
            ax += gu * u4.x; ay += gu * u4.y; az += gu * u4.z;
        } else {
            const ushort_t* vj = &vh_old[jb + (size_t)tt * 3];
            ax += gu * u4.x + gv * bf2f(vj[0]);
            ay += gu * u4.y + gv * bf2f(vj[1]);
            az += gu * u4.z + gv * bf2f(vj[2]);
        }
        j = jn;
    }
    size_t so = (size_t)node * 128 + tt;
    float snew = s_acc[so] + dsv;
    size_t ib = (size_t)node * 384 + (size_t)tt * 3;
    float vx = L0 ? ax : v_old[ib]     + ax;
    float vy = L0 ? ay : v_old[ib + 1] + ay;
    float vz = L0 ? az : v_old[ib + 2] + az;
    if (LAST) {
        stout(out, so, snew, isbf);
        size_t ob = (size_t)N * 128 + ib;
        stout(out, ob,     vx, isbf);
        stout(out, ob + 1, vy, isbf);
        stout(out, ob + 2, vz, isbf);
    } else {
        s_acc[so] = snew;
        ushort_t hi = f2bf(snew);
        s_hi[so] = hi;
        s_lo[so] = f2bf(snew - bf2f(hi));
        v_new[ib] = vx; v_new[ib + 1] = vy; v_new[ib + 2] = vz;
        vh_new[ib]     = f2bf(vx);
        vh_new[ib + 1] = f2bf(vy);
        vh_new[ib + 2] = f2bf(vz);
    }
}

extern "C" void kernel_launch(void* const* d_in, const int* in_sizes, int n_in,
                              void* d_out, int out_size, void* d_ws, size_t ws_size,
                              hipStream_t stream) {
    const int N = in_sizes[0] / 3;
    const int E = in_sizes[1] / 2;
    const void* xyz  = d_in[0];
    const int*  nbr  = (const int*)d_in[1];
    const void* cg_s = d_in[2];
    const void* W1   = d_in[3];
    const void* b1   = d_in[4];
    const void* W2   = d_in[5];
    const void* b2   = d_in[6];
    const void* Wr   = d_in[7];
    const void* br   = d_in[8];

    size_t off = 0;
    auto alloc = [&](size_t bytes) -> char* {
        char* p = (char*)d_ws + off;
        off = (off + bytes + 63) & ~(size_t)63;
        return p;
    };
    int*       flag   = (int*)alloc(64);
    float*     s_acc  = (float*)alloc((size_t)N * 128 * 4);
    float*     vA     = (float*)alloc((size_t)N * 384 * 4);
    float*     vB     = (float*)alloc((size_t)N * 384 * 4);
    int*       cursor = (int*)alloc((size_t)N * 4);
    int*       jlist  = (int*)alloc((size_t)N * DMAX * 4);
    float4*    upos   = (float4*)alloc((size_t)N * DMAX * 16);
    _Float16*  rbfh   = (_Float16*)alloc((size_t)N * DMAX * KAUG * 2);
    _Float16*  WrT    = (_Float16*)alloc((size_t)3 * 384 * KAUG * 2);
    ushort_t*  s_hi   = (ushort_t*)alloc((size_t)N * 128 * 2);
    ushort_t*  s_lo   = (ushort_t*)alloc((size_t)N * 128 * 2);
    ushort_t*  h_hi   = (ushort_t*)alloc((size_t)N * 128 * 2);
    ushort_t*  h_lo   = (ushort_t*)alloc((size_t)N * 128 * 2);
    ushort_t*  phi    = (ushort_t*)alloc((size_t)N * 384 * 2);
    ushort_t*  vhA    = (ushort_t*)alloc((size_t)N * 384 * 2);
    ushort_t*  vhB    = (ushort_t*)alloc((size_t)N * 384 * 2);
    ushort_t*  B1hi   = (ushort_t*)alloc((size_t)3 * 4 * 8 * 64 * 8 * 2);
    ushort_t*  B1lo   = (ushort_t*)alloc((size_t)3 * 4 * 8 * 64 * 8 * 2);
    ushort_t*  B2hi   = (ushort_t*)alloc((size_t)3 * 4 * 24 * 64 * 8 * 2);
    ushort_t*  B2lo   = (ushort_t*)alloc((size_t)3 * 4 * 24 * 64 * 8 * 2);

    detect_kernel<<<(N + 255) / 256, 256, 0, stream>>>(xyz, flag, cursor, N);

    const int N128 = N * 128;
    const int pg = (max(E, N128) + 255) / 256;
    prep_kernel<<<pg, 256, 0, stream>>>(xyz, nbr, cg_s, W1, W2, Wr, br,
                                        s_acc, s_hi, s_lo, cursor,
                                        jlist, upos, rbfh,
                                        B1hi, B1lo, B2hi, B2lo, WrT,
                                        N128, E, flag);

    const int gx = (N + 63) / 64;
    const int gx2 = (gx + 1) / 2;   // RG=2 row-groups per block (measured best)
    for (int l = 0; l < 3; l++) {
        mfma_gemm_rg<1, 0, 8, 2><<<gx2 * 8, 256, 0, stream>>>(
            s_hi, s_lo,
            B1hi + (size_t)l * 4 * 8 * 64 * 8, B1lo + (size_t)l * 4 * 8 * 64 * 8,
            b1, (size_t)l * 128, h_hi, h_lo, N, flag);
        mfma_gemm_rg<0, 1, 24, 2><<<gx2 * 24, 256, 0, stream>>>(
            h_hi, h_lo,
            B2hi + (size_t)l * 4 * 24 * 64 * 8, B2lo + (size_t)l * 4 * 24 * 64 * 8,
            b2, (size_t)l * 384, phi, (ushort_t*)nullptr, N, flag);
        const _Float16* wrt = WrT + (size_t)l * 384 * KAUG;
        if (l == 0) {
            node_kernel<1, 0><<<N, 128, 0, stream>>>(
                cursor, jlist, upos, rbfh, wrt, phi,
                vA, vhA, s_acc, s_hi, s_lo, vA, vhA, d_out, N, flag);
        } else if (l == 1) {
            node_kernel<0, 0><<<N, 128, 0, stream>>>(
                cursor, jlist, upos, rbfh, wrt, phi,
                vA, vhA, s_acc, s_hi, s_lo, vB, vhB, d_out, N, flag);
        } else {
            node_kernel<0, 1><<<N, 128, 0, stream>>>(
                cursor, jlist, upos, rbfh, wrt, phi,
                vB, vhB, s_acc, s_hi, s_lo, vB, vhB, d_out, N, flag);
        }
    }
}